// Round 14
// baseline (2547.958 us; speedup 1.0000x reference)
//
#include <hip/hip_runtime.h>

#define CD 128   // channels
#define KK 9     // 3x3 kernel taps

typedef __bf16 bf16x8 __attribute__((ext_vector_type(8)));
typedef float  f32x4  __attribute__((ext_vector_type(4)));
typedef float  f32x16 __attribute__((ext_vector_type(16)));

typedef __attribute__((address_space(1))) const void* gas_ptr;
typedef __attribute__((address_space(3))) void*       las_ptr;

// ---------------------------------------------------------------------------
// Prep kernel: blocks 0..17 transpose+cast W (tile via LDS); blocks 18+ do
// the linear feats f32->bf16 cast (fb16 doubles as conv2's residual source:
// 51MB, L3-resident — R13 verified this cuts conv2 FETCH 120->95MB).
// ---------------------------------------------------------------------------
#define CAST_BLOCKS 2030
__global__ __launch_bounds__(256) void prep_kernel(
    const float* __restrict__ feats, unsigned short* __restrict__ fb16,
    const float* __restrict__ W1, const float* __restrict__ W2,
    unsigned short* __restrict__ W1T, unsigned short* __restrict__ W2T,
    const long total8) {
    if (blockIdx.x < 2 * KK) {
        __shared__ unsigned short tile[128 * 129];
        const int b = blockIdx.x;            // 0..17
        const int k = (b < KK) ? b : b - KK;
        const float* src = ((b < KK) ? W1 : W2) + k * (CD * CD);
        unsigned short* dst = ((b < KK) ? W1T : W2T) + k * (CD * CD);
        #pragma unroll 4
        for (int p = 0; p < 64; ++p) {
            int idx = p * 256 + threadIdx.x;     // coalesced read W[k][c][o]
            int c = idx >> 7, o = idx & 127;
            __bf16 h = (__bf16)src[idx];
            tile[o * 129 + c] = __builtin_bit_cast(unsigned short, h);
        }
        __syncthreads();
        #pragma unroll 4
        for (int p = 0; p < 64; ++p) {
            int idx = p * 256 + threadIdx.x;     // coalesced write W_T[k][o][c]
            int o = idx >> 7, c = idx & 127;
            dst[idx] = tile[o * 129 + c];
        }
    } else {
        const long stride = (long)CAST_BLOCKS * 256;
        for (long i = (long)(blockIdx.x - 2 * KK) * 256 + threadIdx.x;
             i < total8; i += stride) {
            f32x4 lo = *(const f32x4*)(feats + i * 8);
            f32x4 hi = *(const f32x4*)(feats + i * 8 + 4);
            bf16x8 v;
            #pragma unroll
            for (int e = 0; e < 4; ++e) {
                v[e]     = (__bf16)lo[e];
                v[e + 4] = (__bf16)hi[e];
            }
            *(bf16x8*)(fb16 + i * 8) = v;
        }
    }
}

// ---------------------------------------------------------------------------
// Conv body, R14: occupancy-for-LDS trade on the R13 structure.
//  - wave = 64 sites x 128 out (acc 128 AGPR); 256-thr block.
//  - SINGLE-buffered 32KB weight LDS (was 2x32KB) -> 4-5 blocks/CU
//    (LDS 160KB cap) -> 16-20 waves/CU vs 8. R13's Occupancy=15% showed
//    LDS, not VGPR (pool 2048/SIMD vs ~220/wave), capped residency.
//  - tap loop: MFMA(k) -> barrier -> [stage(k+1) + gather A(k+1) +
//    nbr(k+2)] -> barrier. One A-reg set gathered one tap ahead (lifetime
//    crosses one barrier; no second buffer -- R11 spill lesson). Indices
//    roll two taps ahead; validity masked at use. The drain barrier is
//    covered by the other 3-4 resident blocks' MFMA phases.
//  - XOR swizzle on global source (linear LDS dest), same XOR on ds_read.
//  - conv2: in-place residual epilogue, bf16 resid from fb16 (R13-verified).
// ---------------------------------------------------------------------------
template <bool FIRST>
__device__ __forceinline__ void conv_body(
    const unsigned short* __restrict__ asrc,   // bf16 A source [n][128]
    const unsigned short* __restrict__ resid,  // bf16 residual (!FIRST)
    const unsigned short* __restrict__ WT,     // bf16 W_T[k][o][c] linear
    const int* __restrict__ nbr,               // [n][9]
    unsigned short* __restrict__ hout,         // bf16 out (FIRST)
    float* __restrict__ fout,                  // f32 out (!FIRST)
    const int n, char* wbuf)                   // 32KB single buffer
{
    const int tid  = threadIdx.x;
    const int lane = tid & 63;
    const int l31  = lane & 31;
    const int kh   = lane >> 5;
    const int wave = tid >> 6;
    const int base = blockIdx.x * 256 + wave * 64;
    const int s0 = base + l31;
    const int s1 = base + 32 + l31;
    const int sc0 = (s0 < n) ? s0 : (n - 1);
    const int sc1 = (s1 < n) ? s1 : (n - 1);

    auto stage = [&](int k) {
        const char* tap = (const char*)(WT + (size_t)k * CD * CD);
        #pragma unroll
        for (int i = 0; i < 8; ++i) {
            const int chunk = (i * 4 + wave) * 1024;
            const int d = chunk + lane * 16;
            const int s = d ^ (((d >> 8) & 7) << 4);
            __builtin_amdgcn_global_load_lds((gas_ptr)(tap + s),
                                             (las_ptr)(wbuf + chunk), 16, 0, 0);
        }
    };

    f32x16 acc[2][4];
    #pragma unroll
    for (int m = 0; m < 2; ++m)
        #pragma unroll
        for (int nf = 0; nf < 4; ++nf)
            #pragma unroll
            for (int i = 0; i < 16; ++i) acc[m][nf][i] = 0.f;

    bf16x8 zed;
    #pragma unroll
    for (int e = 0; e < 8; ++e) zed[e] = (__bf16)0.f;

    bf16x8 a0[8], a1[8];
    bool v0, v1;
    int c0, c1;       // rolling neighbor indices (one tap ahead of gathers)

    // prologue: stage tap0, gather A(0), preload idx for tap1
    {
        const int i0 = nbr[(size_t)sc0 * KK];
        const int i1 = nbr[(size_t)sc1 * KK];
        stage(0);
        v0 = (unsigned)i0 < (unsigned)n;
        v1 = (unsigned)i1 < (unsigned)n;
        const size_t rr0 = (size_t)(v0 ? i0 : 0) * CD;
        const size_t rr1 = (size_t)(v1 ? i1 : 0) * CD;
        #pragma unroll
        for (int cs = 0; cs < 8; ++cs) {
            const int coff = cs * 16 + kh * 8;
            a0[cs] = *(const bf16x8*)(asrc + rr0 + coff);
            a1[cs] = *(const bf16x8*)(asrc + rr1 + coff);
        }
        c0 = nbr[(size_t)sc0 * KK + 1];
        c1 = nbr[(size_t)sc1 * KK + 1];
    }
    __syncthreads();   // wbuf has tap0; A(0) drained

    const int swq = (l31 & 7) << 4;

    #pragma unroll 1
    for (int k = 0; k < KK; ++k) {
        // ---- MFMA phase: A in regs (masked at use), B from LDS ----
        #pragma unroll
        for (int cs = 0; cs < 8; ++cs) {
            const bf16x8 am0 = v0 ? a0[cs] : zed;
            const bf16x8 am1 = v1 ? a1[cs] : zed;
            #pragma unroll
            for (int nf = 0; nf < 4; ++nf) {
                const int x = ((nf * 32 + l31) << 8) + (cs << 5) + (kh << 4);
                bf16x8 b = *(const bf16x8*)(wbuf + (x ^ swq));
                acc[0][nf] = __builtin_amdgcn_mfma_f32_32x32x16_bf16(am0, b, acc[0][nf], 0, 0, 0);
                acc[1][nf] = __builtin_amdgcn_mfma_f32_32x32x16_bf16(am1, b, acc[1][nf], 0, 0, 0);
            }
        }

        __syncthreads();   // all waves done reading wbuf(k)

        if (k + 1 < KK) {
            // ---- covered window: restage weights + next-tap gathers ----
            stage(k + 1);
            const bool nv0 = (unsigned)c0 < (unsigned)n;
            const bool nv1 = (unsigned)c1 < (unsigned)n;
            const size_t rr0 = (size_t)(nv0 ? c0 : 0) * CD;
            const size_t rr1 = (size_t)(nv1 ? c1 : 0) * CD;
            #pragma unroll
            for (int cs = 0; cs < 8; ++cs) {
                const int coff = cs * 16 + kh * 8;
                a0[cs] = *(const bf16x8*)(asrc + rr0 + coff);
                a1[cs] = *(const bf16x8*)(asrc + rr1 + coff);
            }
            v0 = nv0; v1 = nv1;
            if (k + 2 < KK) {
                c0 = nbr[(size_t)sc0 * KK + k + 2];
                c1 = nbr[(size_t)sc1 * KK + k + 2];
            }
            __syncthreads();   // drain: wbuf(k+1) + A(k+1) resident
        }
    }

    // Epilogue: C/D map col=lane&31, row=(rg&3)+8*(rg>>2)+4*kh.
    // conv2: residual add in place (adjacent read+write of each out line).
    #pragma unroll
    for (int m = 0; m < 2; ++m) {
        #pragma unroll
        for (int rg = 0; rg < 16; ++rg) {
            const int row  = (rg & 3) + 8 * (rg >> 2) + 4 * kh;
            const int srow = base + m * 32 + row;
            if (srow < n) {
                #pragma unroll
                for (int nf = 0; nf < 4; ++nf) {
                    float v = acc[m][nf][rg];
                    const size_t oi = (size_t)srow * CD + nf * 32 + l31;
                    if (FIRST) {
                        v = v > 0.f ? v : 0.f;
                        hout[oi] = __builtin_bit_cast(unsigned short, (__bf16)v);
                    } else {
                        const __bf16 rb = __builtin_bit_cast(__bf16, resid[oi]);
                        v += (float)rb;
                        v = v > 0.f ? v : 0.f;
                        fout[oi] = v;
                    }
                }
            }
        }
    }
}

__global__ __launch_bounds__(256, 4) void conv1_kernel(
    const unsigned short* __restrict__ fb16,
    const unsigned short* __restrict__ WT,
    const int* __restrict__ nbr,
    unsigned short* __restrict__ hout,
    const int n)
{
    __shared__ __align__(16) char wbuf[32768];
    conv_body<true>(fb16, nullptr, WT, nbr, hout, nullptr, n, wbuf);
}

__global__ __launch_bounds__(256, 4) void conv2_kernel(
    const unsigned short* __restrict__ hid,
    const unsigned short* __restrict__ fb16,   // bf16 residual source
    const unsigned short* __restrict__ WT,
    const int* __restrict__ nbr,
    float* __restrict__ fout,
    const int n)
{
    __shared__ __align__(16) char wbuf[32768];
    conv_body<false>(hid, fb16, WT, nbr, nullptr, fout, n, wbuf);
}

extern "C" void kernel_launch(void* const* d_in, const int* in_sizes, int n_in,
                              void* d_out, int out_size, void* d_ws, size_t ws_size,
                              hipStream_t stream) {
    const float* feats = (const float*)d_in[0];
    const int*   nbr   = (const int*)d_in[1];
    const float* W1    = (const float*)d_in[2];
    const float* W2    = (const float*)d_in[3];
    float* out = (float*)d_out;

    const int n = in_sizes[0] / CD;   // active sites (200000)

    // workspace layout: hid [n][128] bf16, W1T, W2T, fbf16 [n][128] bf16
    unsigned short* hid  = (unsigned short*)d_ws;
    unsigned short* W1T  = hid + (size_t)n * CD;
    unsigned short* W2T  = W1T + KK * CD * CD;
    unsigned short* fb16 = W2T + KK * CD * CD;
    (void)ws_size;

    const long total8 = (long)n * CD / 8;
    prep_kernel<<<2 * KK + CAST_BLOCKS, 256, 0, stream>>>(
        feats, fb16, W1, W2, W1T, W2T, total8);

    const int grid = (n + 255) / 256;   // 256 sites per 4-wave block
    conv1_kernel<<<grid, 256, 0, stream>>>(fb16, W1T, nbr, hid, n);
    conv2_kernel<<<grid, 256, 0, stream>>>(hid, fb16, W2T, nbr, out, n);
}

// Round 15
// 233.554 us; speedup vs baseline: 10.9095x; 10.9095x over previous
//
#include <hip/hip_runtime.h>

#define CD 128   // channels
#define KK 9     // 3x3 kernel taps

typedef __bf16 bf16x8 __attribute__((ext_vector_type(8)));
typedef float  f32x4  __attribute__((ext_vector_type(4)));
typedef float  f32x16 __attribute__((ext_vector_type(16)));

typedef __attribute__((address_space(1))) const void* gas_ptr;
typedef __attribute__((address_space(3))) void*       las_ptr;

// ---------------------------------------------------------------------------
// Prep kernel: blocks 0..17 transpose+cast W (tile via LDS); blocks 18+ do
// the linear feats f32->bf16 cast (fb16 doubles as conv2's residual source:
// 51MB, L3-resident — R13 verified this cuts conv2 FETCH 120->95MB).
// ---------------------------------------------------------------------------
#define CAST_BLOCKS 2030
__global__ __launch_bounds__(256) void prep_kernel(
    const float* __restrict__ feats, unsigned short* __restrict__ fb16,
    const float* __restrict__ W1, const float* __restrict__ W2,
    unsigned short* __restrict__ W1T, unsigned short* __restrict__ W2T,
    const long total8) {
    if (blockIdx.x < 2 * KK) {
        __shared__ unsigned short tile[128 * 129];
        const int b = blockIdx.x;            // 0..17
        const int k = (b < KK) ? b : b - KK;
        const float* src = ((b < KK) ? W1 : W2) + k * (CD * CD);
        unsigned short* dst = ((b < KK) ? W1T : W2T) + k * (CD * CD);
        #pragma unroll 4
        for (int p = 0; p < 64; ++p) {
            int idx = p * 256 + threadIdx.x;     // coalesced read W[k][c][o]
            int c = idx >> 7, o = idx & 127;
            __bf16 h = (__bf16)src[idx];
            tile[o * 129 + c] = __builtin_bit_cast(unsigned short, h);
        }
        __syncthreads();
        #pragma unroll 4
        for (int p = 0; p < 64; ++p) {
            int idx = p * 256 + threadIdx.x;     // coalesced write W_T[k][o][c]
            int o = idx >> 7, c = idx & 127;
            dst[idx] = tile[o * 129 + c];
        }
    } else {
        const long stride = (long)CAST_BLOCKS * 256;
        for (long i = (long)(blockIdx.x - 2 * KK) * 256 + threadIdx.x;
             i < total8; i += stride) {
            f32x4 lo = *(const f32x4*)(feats + i * 8);
            f32x4 hi = *(const f32x4*)(feats + i * 8 + 4);
            bf16x8 v;
            #pragma unroll
            for (int e = 0; e < 4; ++e) {
                v[e]     = (__bf16)lo[e];
                v[e + 4] = (__bf16)hi[e];
            }
            *(bf16x8*)(fb16 + i * 8) = v;
        }
    }
}

// ---------------------------------------------------------------------------
// Conv body, R15 = EXACT R13 (205us total: conv1@68, conv2@105) + IN-PLACE
// A reload: during tap k's MFMA phase, each a[cs] is copied to a masked
// temp, fed to its 4 MFMAs, then immediately overwritten with tap-(k+1)'s
// gather. Reloads are covered by the remaining MFMAs + the barrier; the
// next tap's MFMA phase starts with A already resident -> the ~400cy/tap
// exposed gather wait disappears. Register budget (R14 lesson: per-SIMD
// pool = 512 regs -> 2 waves/SIMD cap for this 256-reg/wave shape): adds
// only next-row addresses (~6 VGPR) -- NO second A buffer (R11 spill).
// Guard signal: conv2 WRITE must stay exactly 100000 KiB (no scratch).
//  - wave = 64 sites x 128 out, 256-thr block, 2 waves/SIMD.
//  - weights double-buffered 2x32KB LDS via global_load_lds w=16, XOR
//    swizzle on the GLOBAL source (linear LDS dest), same XOR on ds_read.
//  - conv2: in-place residual epilogue, bf16 resid from fb16 (R13).
// ---------------------------------------------------------------------------
template <bool FIRST>
__device__ __forceinline__ void conv_body(
    const unsigned short* __restrict__ asrc,   // bf16 A source [n][128]
    const unsigned short* __restrict__ resid,  // bf16 residual (!FIRST)
    const unsigned short* __restrict__ WT,     // bf16 W_T[k][o][c] linear
    const int* __restrict__ nbr,               // [n][9]
    unsigned short* __restrict__ hout,         // bf16 out (FIRST)
    float* __restrict__ fout,                  // f32 out (!FIRST)
    const int n, char (*wbuf)[32768])
{
    const int tid  = threadIdx.x;
    const int lane = tid & 63;
    const int l31  = lane & 31;
    const int kh   = lane >> 5;
    const int wave = tid >> 6;
    const int base = blockIdx.x * 256 + wave * 64;
    const int s0 = base + l31;
    const int s1 = base + 32 + l31;
    const int sc0 = (s0 < n) ? s0 : (n - 1);
    const int sc1 = (s1 < n) ? s1 : (n - 1);

    auto stage = [&](int b, int k) {
        const char* tap = (const char*)(WT + (size_t)k * CD * CD);
        char* lb = &wbuf[b][0];
        #pragma unroll
        for (int i = 0; i < 8; ++i) {
            const int chunk = (i * 4 + wave) * 1024;
            const int d = chunk + lane * 16;
            const int s = d ^ (((d >> 8) & 7) << 4);
            __builtin_amdgcn_global_load_lds((gas_ptr)(tap + s),
                                             (las_ptr)(lb + chunk), 16, 0, 0);
        }
    };

    f32x16 acc[2][4];
    #pragma unroll
    for (int m = 0; m < 2; ++m)
        #pragma unroll
        for (int nf = 0; nf < 4; ++nf)
            #pragma unroll
            for (int i = 0; i < 16; ++i) acc[m][nf][i] = 0.f;

    bf16x8 zed;
    #pragma unroll
    for (int e = 0; e < 8; ++e) zed[e] = (__bf16)0.f;

    bf16x8 a0[8], a1[8];
    bool vcur0, vcur1;
    int c0, c1;    // indices for tap k+1 (rolled two ahead)

    // prologue: raw-gather A(0) (masked at use), stage tap0, idx for tap1
    {
        const int i0 = nbr[(size_t)sc0 * KK];
        const int i1 = nbr[(size_t)sc1 * KK];
        vcur0 = (unsigned)i0 < (unsigned)n;
        vcur1 = (unsigned)i1 < (unsigned)n;
        const size_t rr0 = (size_t)(vcur0 ? i0 : 0) * CD;
        const size_t rr1 = (size_t)(vcur1 ? i1 : 0) * CD;
        #pragma unroll
        for (int cs = 0; cs < 8; ++cs) {
            const int coff = cs * 16 + kh * 8;
            a0[cs] = *(const bf16x8*)(asrc + rr0 + coff);
            a1[cs] = *(const bf16x8*)(asrc + rr1 + coff);
        }
    }
    stage(0, 0);
    c0 = nbr[(size_t)sc0 * KK + 1];
    c1 = nbr[(size_t)sc1 * KK + 1];
    __syncthreads();

    const int swq = (l31 & 7) << 4;

    #pragma unroll 1
    for (int k = 0; k < KK; ++k) {
        const bool last = (k + 1 >= KK);

        // next-tap validity + row addresses (for the in-place reloads)
        const bool vn0 = (unsigned)c0 < (unsigned)n;
        const bool vn1 = (unsigned)c1 < (unsigned)n;
        const size_t rrn0 = (size_t)(vn0 ? c0 : 0) * CD;
        const size_t rrn1 = (size_t)(vn1 ? c1 : 0) * CD;

        // weight staging for tap k+1 (dbuf; covered by this tap's MFMAs)
        if (!last) stage((k + 1) & 1, k + 1);

        // roll indices two ahead
        int cnn0 = 0, cnn1 = 0;
        if (k + 2 < KK) {
            cnn0 = nbr[(size_t)sc0 * KK + k + 2];
            cnn1 = nbr[(size_t)sc1 * KK + k + 2];
        }

        // ---- MFMA phase with in-place reload ----
        const char* wb = &wbuf[k & 1][0];
        #pragma unroll
        for (int cs = 0; cs < 8; ++cs) {
            const bf16x8 am0 = vcur0 ? a0[cs] : zed;   // masked copy
            const bf16x8 am1 = vcur1 ? a1[cs] : zed;
            if (!last) {                               // reload for tap k+1
                const int coff = cs * 16 + kh * 8;
                a0[cs] = *(const bf16x8*)(asrc + rrn0 + coff);
                a1[cs] = *(const bf16x8*)(asrc + rrn1 + coff);
            }
            #pragma unroll
            for (int nf = 0; nf < 4; ++nf) {
                const int x = ((nf * 32 + l31) << 8) + (cs << 5) + (kh << 4);
                bf16x8 b = *(const bf16x8*)(wb + (x ^ swq));
                acc[0][nf] = __builtin_amdgcn_mfma_f32_32x32x16_bf16(am0, b, acc[0][nf], 0, 0, 0);
                acc[1][nf] = __builtin_amdgcn_mfma_f32_32x32x16_bf16(am1, b, acc[1][nf], 0, 0, 0);
            }
        }

        __syncthreads();   // drains stage(k+1) + reloads (both MFMA-covered)
        vcur0 = vn0; vcur1 = vn1;
        c0 = cnn0; c1 = cnn1;
    }

    // Epilogue: C/D map col=lane&31, row=(rg&3)+8*(rg>>2)+4*kh.
    // conv2: residual add in place (adjacent read+write of each out line).
    #pragma unroll
    for (int m = 0; m < 2; ++m) {
        #pragma unroll
        for (int rg = 0; rg < 16; ++rg) {
            const int row  = (rg & 3) + 8 * (rg >> 2) + 4 * kh;
            const int srow = base + m * 32 + row;
            if (srow < n) {
                #pragma unroll
                for (int nf = 0; nf < 4; ++nf) {
                    float v = acc[m][nf][rg];
                    const size_t oi = (size_t)srow * CD + nf * 32 + l31;
                    if (FIRST) {
                        v = v > 0.f ? v : 0.f;
                        hout[oi] = __builtin_bit_cast(unsigned short, (__bf16)v);
                    } else {
                        const __bf16 rb = __builtin_bit_cast(__bf16, resid[oi]);
                        v += (float)rb;
                        v = v > 0.f ? v : 0.f;
                        fout[oi] = v;
                    }
                }
            }
        }
    }
}

__global__ __launch_bounds__(256, 2) void conv1_kernel(
    const unsigned short* __restrict__ fb16,
    const unsigned short* __restrict__ WT,
    const int* __restrict__ nbr,
    unsigned short* __restrict__ hout,
    const int n)
{
    __shared__ __align__(16) char wbuf[2][32768];
    conv_body<true>(fb16, nullptr, WT, nbr, hout, nullptr, n, wbuf);
}

__global__ __launch_bounds__(256, 2) void conv2_kernel(
    const unsigned short* __restrict__ hid,
    const unsigned short* __restrict__ fb16,   // bf16 residual source
    const unsigned short* __restrict__ WT,
    const int* __restrict__ nbr,
    float* __restrict__ fout,
    const int n)
{
    __shared__ __align__(16) char wbuf[2][32768];
    conv_body<false>(hid, fb16, WT, nbr, nullptr, fout, n, wbuf);
}

extern "C" void kernel_launch(void* const* d_in, const int* in_sizes, int n_in,
                              void* d_out, int out_size, void* d_ws, size_t ws_size,
                              hipStream_t stream) {
    const float* feats = (const float*)d_in[0];
    const int*   nbr   = (const int*)d_in[1];
    const float* W1    = (const float*)d_in[2];
    const float* W2    = (const float*)d_in[3];
    float* out = (float*)d_out;

    const int n = in_sizes[0] / CD;   // active sites (200000)

    // workspace layout: hid [n][128] bf16, W1T, W2T, fbf16 [n][128] bf16
    unsigned short* hid  = (unsigned short*)d_ws;
    unsigned short* W1T  = hid + (size_t)n * CD;
    unsigned short* W2T  = W1T + KK * CD * CD;
    unsigned short* fb16 = W2T + KK * CD * CD;
    (void)ws_size;

    const long total8 = (long)n * CD / 8;
    prep_kernel<<<2 * KK + CAST_BLOCKS, 256, 0, stream>>>(
        feats, fb16, W1, W2, W1T, W2T, total8);

    const int grid = (n + 255) / 256;   // 256 sites per 4-wave block
    conv1_kernel<<<grid, 256, 0, stream>>>(fb16, W1T, nbr, hid, n);
    conv2_kernel<<<grid, 256, 0, stream>>>(hid, fb16, W2T, nbr, out, n);
}